// Round 25
// baseline (15.482 us; speedup 1.0000x reference)
//
#include <hip/hip_runtime.h>
#include <math.h>

#define L 512
#define LPAD 544          // s_mi padded: rows 512..543 = {0,0} -> p==0 naturally
#define NTHREADS 256
#define BLOCK_TT 32       // two 16-t sub-tiles; shared prologue AND shared B-gather
#define ZWIN 9.0f         // dropped pdf mass <= exp(-40.5): < 1e-10 effect on output
#define NXCD 8

typedef __attribute__((ext_vector_type(8))) short bf16x8;
typedef __attribute__((ext_vector_type(4))) float f32x4;

static constexpr float EPS = 1e-6f;
static constexpr float INV_SQRT_2PI = 0.39894228040143267794f;

union BFrag { unsigned int u[4]; uint4 q; bf16x8 h; };

__global__ __launch_bounds__(NTHREADS, 4) void ge_mfma(
    const int*   __restrict__ durs,  // [B, L]
    const float* __restrict__ text,  // [B, L, 256]
    float*       __restrict__ out,   // [B, T, 256]
    int B, int T, int tilesPerB, int nwg)
{
    __shared__ float2 s_mi[LPAD];
    __shared__ uint4  s_af[2][2][64];   // [buf][half][lane] A fragments (bf16x8)
    __shared__ float  s_ps[2][16];      // per-half psum accumulators

    const int tid  = threadIdx.x;
    const int lane = tid & 63;
    const int wid  = tid >> 6;
    const int g    = lane >> 4;      // k-group (A/B), C row-group
    const int mrow = lane & 15;      // A-row (t offset) == B/C-col (d offset)

    const int orig = blockIdx.x;
    const int wg   = (nwg % NXCD == 0) ? (orig & (NXCD - 1)) * (nwg / NXCD) + (orig >> 3)
                                       : orig;
    const int b      = wg / tilesPerB;
    const int tbase0 = (wg % tilesPerB) * BLOCK_TT;

    // ---- wave-private scan, once per block: lane owns rows 8*lane..8*lane+7 ----
    const int r0 = lane << 3;
    const int4 da = ((const int4*)(durs + (size_t)b * L + r0))[0];
    const int4 db = ((const int4*)(durs + (size_t)b * L + r0))[1];
    int dv[8] = {da.x, da.y, da.z, da.w, db.x, db.y, db.z, db.w};
    int cs[8];
    int run = 0;
    #pragma unroll
    for (int j = 0; j < 8; ++j) { run += dv[j]; cs[j] = run; }
    int v = run;
    #pragma unroll
    for (int off = 1; off < 64; off <<= 1) {
        int n = __shfl_up(v, off, 64);
        if (lane >= off) v += n;
    }
    const int excl = v - run;

    // ---- params to LDS (+ zero pads) + UNION band over the 32-t block ----
    const float tlo = (float)tbase0 + 0.5f;
    const float thi = (float)tbase0 + (float)BLOCK_TT - 0.5f;
    int mn = L, mx = -1;
    #pragma unroll
    for (int j = 0; j < 8; ++j) {
        const float d  = (float)dv[j];
        const float m  = (float)(cs[j] + excl) + 0.5f * d;
        const float sg = 0.5f * d + EPS;
        s_mi[r0 + j] = make_float2(m, 1.0f / sg);
        const float r = ZWIN * sg;
        if (dv[j] >= 1 && m + r >= tlo && m - r <= thi) {
            mn = min(mn, r0 + j);
            mx = max(mx, r0 + j);
        }
    }
    if (tid < LPAD - L) s_mi[L + tid] = make_float2(0.f, 0.f);  // isig==0 -> p==0
    if (tid < 32) s_ps[tid >> 4][tid & 15] = 0.f;
    #pragma unroll
    for (int off = 32; off > 0; off >>= 1) {
        mn = min(mn, __shfl_xor(mn, off, 64));
        mx = max(mx, __shfl_xor(mx, off, 64));
    }
    __syncthreads();   // s_mi/s_ps init visible to all waves

    // ---- main loop: waves 0,1 produce A (once), all waves gather B + MFMA ----
    f32x4 a00 = {0,0,0,0}, a01 = {0,0,0,0}, a02 = {0,0,0,0}, a03 = {0,0,0,0};  // half 0
    f32x4 a10 = {0,0,0,0}, a11 = {0,0,0,0}, a12 = {0,0,0,0}, a13 = {0,0,0,0};  // half 1
    const float* tbp = text + (size_t)b * L * 256 + (wid << 6) + mrow;
    int p = 0;

    for (int kb = (mn & ~7); kb <= mx; kb += 32) {
        const int k0 = kb + (g << 3);

        // B fragments (all waves): 32 independent loads issue under the A-exp chain
        BFrag B0, B1, B2, B3;
        #pragma unroll
        for (int jp = 0; jp < 4; ++jp) {
            const int ka = min(k0 + 2 * jp,     L - 1);   // p==0 past L-1: garbage*0 == 0
            const int kc = min(k0 + 2 * jp + 1, L - 1);
            const float* ra = tbp + (size_t)ka * 256;
            const float* rc = tbp + (size_t)kc * 256;
            const float b0 = ra[0], b1 = ra[16], b2 = ra[32], b3 = ra[48];
            const float c0 = rc[0], c1 = rc[16], c2 = rc[32], c3 = rc[48];
            asm("v_cvt_pk_bf16_f32 %0, %1, %2" : "=v"(B0.u[jp]) : "v"(b0), "v"(c0));
            asm("v_cvt_pk_bf16_f32 %0, %1, %2" : "=v"(B1.u[jp]) : "v"(b1), "v"(c1));
            asm("v_cvt_pk_bf16_f32 %0, %1, %2" : "=v"(B2.u[jp]) : "v"(b2), "v"(c2));
            asm("v_cvt_pk_bf16_f32 %0, %1, %2" : "=v"(B3.u[jp]) : "v"(b3), "v"(c3));
        }

        // A produce (waves 0,1 only; wave == half). Identical per-lane values as before.
        if (wid < 2) {
            const float tf = (float)(tbase0 + (wid << 4) + mrow) + 0.5f;
            float part = 0.f;
            unsigned int u0, u1, u2, u3;
            {
                const float2 mia = s_mi[k0 + 0], mic = s_mi[k0 + 1];
                const float pa = __expf(-0.5f * ((tf - mia.x) * mia.y) * ((tf - mia.x) * mia.y)) * mia.y * INV_SQRT_2PI;
                const float pc = __expf(-0.5f * ((tf - mic.x) * mic.y) * ((tf - mic.x) * mic.y)) * mic.y * INV_SQRT_2PI;
                part += pa + pc;
                asm("v_cvt_pk_bf16_f32 %0, %1, %2" : "=v"(u0) : "v"(pa), "v"(pc));
            }
            {
                const float2 mia = s_mi[k0 + 2], mic = s_mi[k0 + 3];
                const float pa = __expf(-0.5f * ((tf - mia.x) * mia.y) * ((tf - mia.x) * mia.y)) * mia.y * INV_SQRT_2PI;
                const float pc = __expf(-0.5f * ((tf - mic.x) * mic.y) * ((tf - mic.x) * mic.y)) * mic.y * INV_SQRT_2PI;
                part += pa + pc;
                asm("v_cvt_pk_bf16_f32 %0, %1, %2" : "=v"(u1) : "v"(pa), "v"(pc));
            }
            {
                const float2 mia = s_mi[k0 + 4], mic = s_mi[k0 + 5];
                const float pa = __expf(-0.5f * ((tf - mia.x) * mia.y) * ((tf - mia.x) * mia.y)) * mia.y * INV_SQRT_2PI;
                const float pc = __expf(-0.5f * ((tf - mic.x) * mic.y) * ((tf - mic.x) * mic.y)) * mic.y * INV_SQRT_2PI;
                part += pa + pc;
                asm("v_cvt_pk_bf16_f32 %0, %1, %2" : "=v"(u2) : "v"(pa), "v"(pc));
            }
            {
                const float2 mia = s_mi[k0 + 6], mic = s_mi[k0 + 7];
                const float pa = __expf(-0.5f * ((tf - mia.x) * mia.y) * ((tf - mia.x) * mia.y)) * mia.y * INV_SQRT_2PI;
                const float pc = __expf(-0.5f * ((tf - mic.x) * mic.y) * ((tf - mic.x) * mic.y)) * mic.y * INV_SQRT_2PI;
                part += pa + pc;
                asm("v_cvt_pk_bf16_f32 %0, %1, %2" : "=v"(u3) : "v"(pa), "v"(pc));
            }
            // reduce over g (k-octets) within the wave: lanes mrow+16g share a t
            part += __shfl_xor(part, 16, 64);
            part += __shfl_xor(part, 32, 64);
            if (lane < 16) s_ps[wid][lane] += part;   // single writer per slot
            s_af[p][wid][lane] = make_uint4(u0, u1, u2, u3);
        }
        __syncthreads();   // A fragments + psum visible

        BFrag A0, A1;
        A0.q = s_af[p][0][lane];   // contiguous ds_read_b128: conflict-free
        A1.q = s_af[p][1][lane];

        a00 = __builtin_amdgcn_mfma_f32_16x16x32_bf16(A0.h, B0.h, a00, 0, 0, 0);
        a01 = __builtin_amdgcn_mfma_f32_16x16x32_bf16(A0.h, B1.h, a01, 0, 0, 0);
        a02 = __builtin_amdgcn_mfma_f32_16x16x32_bf16(A0.h, B2.h, a02, 0, 0, 0);
        a03 = __builtin_amdgcn_mfma_f32_16x16x32_bf16(A0.h, B3.h, a03, 0, 0, 0);
        a10 = __builtin_amdgcn_mfma_f32_16x16x32_bf16(A1.h, B0.h, a10, 0, 0, 0);
        a11 = __builtin_amdgcn_mfma_f32_16x16x32_bf16(A1.h, B1.h, a11, 0, 0, 0);
        a12 = __builtin_amdgcn_mfma_f32_16x16x32_bf16(A1.h, B2.h, a12, 0, 0, 0);
        a13 = __builtin_amdgcn_mfma_f32_16x16x32_bf16(A1.h, B3.h, a13, 0, 0, 0);
        p ^= 1;   // double-buffer: next chunk writes the other AF buffer
    }

    // ---- epilogue per half: psum from LDS (broadcast), normalize, nt-store ----
    const int trow = g << 2;
    #pragma unroll
    for (int half = 0; half < 2; ++half) {
        const float rr0 = 1.0f / (s_ps[half][trow + 0] + EPS);
        const float rr1 = 1.0f / (s_ps[half][trow + 1] + EPS);
        const float rr2 = 1.0f / (s_ps[half][trow + 2] + EPS);
        const float rr3 = 1.0f / (s_ps[half][trow + 3] + EPS);

        const f32x4 c0 = half ? a10 : a00;
        const f32x4 c1 = half ? a11 : a01;
        const f32x4 c2 = half ? a12 : a02;
        const f32x4 c3 = half ? a13 : a03;

        const int t0 = tbase0 + (half << 4);
        float* ob = out + ((size_t)b * T + t0 + trow) * 256 + (wid << 6) + mrow;
        if (t0 + trow + 3 < T) {
            __builtin_nontemporal_store(c0[0] * rr0, ob + 0*256 +  0);
            __builtin_nontemporal_store(c0[1] * rr1, ob + 1*256 +  0);
            __builtin_nontemporal_store(c0[2] * rr2, ob + 2*256 +  0);
            __builtin_nontemporal_store(c0[3] * rr3, ob + 3*256 +  0);
            __builtin_nontemporal_store(c1[0] * rr0, ob + 0*256 + 16);
            __builtin_nontemporal_store(c1[1] * rr1, ob + 1*256 + 16);
            __builtin_nontemporal_store(c1[2] * rr2, ob + 2*256 + 16);
            __builtin_nontemporal_store(c1[3] * rr3, ob + 3*256 + 16);
            __builtin_nontemporal_store(c2[0] * rr0, ob + 0*256 + 32);
            __builtin_nontemporal_store(c2[1] * rr1, ob + 1*256 + 32);
            __builtin_nontemporal_store(c2[2] * rr2, ob + 2*256 + 32);
            __builtin_nontemporal_store(c2[3] * rr3, ob + 3*256 + 32);
            __builtin_nontemporal_store(c3[0] * rr0, ob + 0*256 + 48);
            __builtin_nontemporal_store(c3[1] * rr1, ob + 1*256 + 48);
            __builtin_nontemporal_store(c3[2] * rr2, ob + 2*256 + 48);
            __builtin_nontemporal_store(c3[3] * rr3, ob + 3*256 + 48);
        }
    }
}

extern "C" void kernel_launch(void* const* d_in, const int* in_sizes, int n_in,
                              void* d_out, int out_size, void* d_ws, size_t ws_size,
                              hipStream_t stream) {
    const int*   durs = (const int*)d_in[1];
    const float* text = (const float*)d_in[0];
    float*       out  = (float*)d_out;

    const int BL = in_sizes[1];        // B * L
    const int D  = in_sizes[0] / BL;   // 256
    const int B  = BL / L;             // 16
    const int T  = out_size / (B * D); // 2048
    const int tilesPerB = (T + BLOCK_TT - 1) / BLOCK_TT;   // 64
    const int nwg = B * tilesPerB;     // 1024

    ge_mfma<<<dim3(nwg), dim3(NTHREADS), 0, stream>>>(durs, text, out, B, T, tilesPerB, nwg);
}

// Round 26
// 15.058 us; speedup vs baseline: 1.0282x; 1.0282x over previous
//
#include <hip/hip_runtime.h>
#include <math.h>

#define L 512
#define LPAD 544          // s_mi padded: rows 512..543 = {0,0} -> p==0 naturally
#define NTHREADS 256
#define BLOCK_TT 32       // two 16-t sub-tiles; shared prologue AND shared B-gather
#define ZWIN 6.5f         // dropped pdf mass <= exp(-21.1) ~ 7.6e-10: invisible at fp32/bf16
#define NXCD 8

typedef __attribute__((ext_vector_type(8))) short bf16x8;
typedef __attribute__((ext_vector_type(4))) float f32x4;

static constexpr float EPS = 1e-6f;
static constexpr float INV_SQRT_2PI = 0.39894228040143267794f;

union BFrag { unsigned int u[4]; bf16x8 h; };

__global__ __launch_bounds__(NTHREADS, 4) void ge_mfma(
    const int*   __restrict__ durs,  // [B, L]
    const float* __restrict__ text,  // [B, L, 256]
    float*       __restrict__ out,   // [B, T, 256]
    int B, int T, int tilesPerB, int nwg)
{
    __shared__ float2 s_mi[LPAD];

    const int tid  = threadIdx.x;
    const int lane = tid & 63;
    const int wid  = tid >> 6;
    const int g    = lane >> 4;      // k-group (A/B), C row-group
    const int mrow = lane & 15;      // A-row (t offset) == B/C-col (d offset)

    const int orig = blockIdx.x;
    const int wg   = (nwg % NXCD == 0) ? (orig & (NXCD - 1)) * (nwg / NXCD) + (orig >> 3)
                                       : orig;
    const int b      = wg / tilesPerB;
    const int tbase0 = (wg % tilesPerB) * BLOCK_TT;

    // ---- wave-private scan, once per block: lane owns rows 8*lane..8*lane+7 ----
    const int r0 = lane << 3;
    const int4 da = ((const int4*)(durs + (size_t)b * L + r0))[0];
    const int4 db = ((const int4*)(durs + (size_t)b * L + r0))[1];
    int dv[8] = {da.x, da.y, da.z, da.w, db.x, db.y, db.z, db.w};
    int cs[8];
    int run = 0;
    #pragma unroll
    for (int j = 0; j < 8; ++j) { run += dv[j]; cs[j] = run; }
    int v = run;
    #pragma unroll
    for (int off = 1; off < 64; off <<= 1) {
        int n = __shfl_up(v, off, 64);
        if (lane >= off) v += n;
    }
    const int excl = v - run;

    // ---- params to LDS (+ zero pads) + UNION band over the 32-t block ----
    const float tlo = (float)tbase0 + 0.5f;
    const float thi = (float)tbase0 + (float)BLOCK_TT - 0.5f;
    int mn = L, mx = -1;
    #pragma unroll
    for (int j = 0; j < 8; ++j) {
        const float d  = (float)dv[j];
        const float m  = (float)(cs[j] + excl) + 0.5f * d;
        const float sg = 0.5f * d + EPS;
        s_mi[r0 + j] = make_float2(m, 1.0f / sg);
        const float r = ZWIN * sg;
        if (dv[j] >= 1 && m + r >= tlo && m - r <= thi) {
            mn = min(mn, r0 + j);
            mx = max(mx, r0 + j);
        }
    }
    if (lane < LPAD - L) s_mi[L + lane] = make_float2(0.f, 0.f);  // isig==0 -> p==0
    #pragma unroll
    for (int off = 32; off > 0; off >>= 1) {
        mn = min(mn, __shfl_xor(mn, off, 64));
        mx = max(mx, __shfl_xor(mx, off, 64));
    }
    asm volatile("s_waitcnt lgkmcnt(0)" ::: "memory");   // own-wave s_mi writes -> reads
    __builtin_amdgcn_sched_barrier(0);

    // ---- main loop over union band: ONE B-gather feeds BOTH 16-t halves ----
    f32x4 a00 = {0,0,0,0}, a01 = {0,0,0,0}, a02 = {0,0,0,0}, a03 = {0,0,0,0};  // half 0
    f32x4 a10 = {0,0,0,0}, a11 = {0,0,0,0}, a12 = {0,0,0,0}, a13 = {0,0,0,0};  // half 1
    float psum0 = 0.f, psum1 = 0.f;
    const float tf0 = (float)(tbase0 + mrow) + 0.5f;    // half0's t for this lane
    const float tf1 = tf0 + 16.f;                       // half1's t
    const float* tbp = text + (size_t)b * L * 256 + (wid << 6) + mrow;

    for (int kb = (mn & ~7); kb <= mx; kb += 32) {
        const int k0 = kb + (g << 3);

        // B fragments FIRST: issue the 32 independent loads under the A-exp chain
        BFrag B0, B1, B2, B3;
        #pragma unroll
        for (int jp = 0; jp < 4; ++jp) {
            const int ka = min(k0 + 2 * jp,     L - 1);   // p==0 past L-1: garbage*0 == 0
            const int kc = min(k0 + 2 * jp + 1, L - 1);
            const float* ra = tbp + (size_t)ka * 256;
            const float* rc = tbp + (size_t)kc * 256;
            const float b0 = ra[0], b1 = ra[16], b2 = ra[32], b3 = ra[48];
            const float c0 = rc[0], c1 = rc[16], c2 = rc[32], c3 = rc[48];
            asm("v_cvt_pk_bf16_f32 %0, %1, %2" : "=v"(B0.u[jp]) : "v"(b0), "v"(c0));
            asm("v_cvt_pk_bf16_f32 %0, %1, %2" : "=v"(B1.u[jp]) : "v"(b1), "v"(c1));
            asm("v_cvt_pk_bf16_f32 %0, %1, %2" : "=v"(B2.u[jp]) : "v"(b2), "v"(c2));
            asm("v_cvt_pk_bf16_f32 %0, %1, %2" : "=v"(B3.u[jp]) : "v"(b3), "v"(c3));
        }

        // A fragments for both halves (no selects; pads/d==0 underflow to 0 naturally)
        BFrag A0, A1;
        #pragma unroll
        for (int jp = 0; jp < 4; ++jp) {
            const int ka = k0 + 2 * jp;          // <= mx+31 <= 542 < LPAD
            const int kc = ka + 1;
            const float2 mia = s_mi[ka];
            const float2 mic = s_mi[kc];
            const float ca = mia.y * INV_SQRT_2PI;
            const float cc = mic.y * INV_SQRT_2PI;
            const float u0a = (tf0 - mia.x) * mia.y;
            const float u0c = (tf0 - mic.x) * mic.y;
            const float u1a = (tf1 - mia.x) * mia.y;
            const float u1c = (tf1 - mic.x) * mic.y;
            const float p0a = __expf(-0.5f * u0a * u0a) * ca;
            const float p0c = __expf(-0.5f * u0c * u0c) * cc;
            const float p1a = __expf(-0.5f * u1a * u1a) * ca;
            const float p1c = __expf(-0.5f * u1c * u1c) * cc;
            psum0 += p0a + p0c;
            psum1 += p1a + p1c;
            asm("v_cvt_pk_bf16_f32 %0, %1, %2" : "=v"(A0.u[jp]) : "v"(p0a), "v"(p0c));
            asm("v_cvt_pk_bf16_f32 %0, %1, %2" : "=v"(A1.u[jp]) : "v"(p1a), "v"(p1c));
        }

        // MFMA cluster under elevated wave priority (waves are free-running: T5 regime)
        __builtin_amdgcn_s_setprio(1);
        a00 = __builtin_amdgcn_mfma_f32_16x16x32_bf16(A0.h, B0.h, a00, 0, 0, 0);
        a01 = __builtin_amdgcn_mfma_f32_16x16x32_bf16(A0.h, B1.h, a01, 0, 0, 0);
        a02 = __builtin_amdgcn_mfma_f32_16x16x32_bf16(A0.h, B2.h, a02, 0, 0, 0);
        a03 = __builtin_amdgcn_mfma_f32_16x16x32_bf16(A0.h, B3.h, a03, 0, 0, 0);
        a10 = __builtin_amdgcn_mfma_f32_16x16x32_bf16(A1.h, B0.h, a10, 0, 0, 0);
        a11 = __builtin_amdgcn_mfma_f32_16x16x32_bf16(A1.h, B1.h, a11, 0, 0, 0);
        a12 = __builtin_amdgcn_mfma_f32_16x16x32_bf16(A1.h, B2.h, a12, 0, 0, 0);
        a13 = __builtin_amdgcn_mfma_f32_16x16x32_bf16(A1.h, B3.h, a13, 0, 0, 0);
        __builtin_amdgcn_s_setprio(0);
    }

    // ---- epilogue per half: shuffle-reduced denominators, normalize, nt-store ----
    const int trow = g << 2;
    #pragma unroll
    for (int half = 0; half < 2; ++half) {
        float ps = half ? psum1 : psum0;
        ps += __shfl_xor(ps, 16, 64);
        ps += __shfl_xor(ps, 32, 64);
        const float rn = 1.0f / (ps + EPS);   // lane (g,mrow): denom for t = t0+mrow

        const float rr0 = __shfl(rn, trow + 0, 64);
        const float rr1 = __shfl(rn, trow + 1, 64);
        const float rr2 = __shfl(rn, trow + 2, 64);
        const float rr3 = __shfl(rn, trow + 3, 64);

        const f32x4 c0 = half ? a10 : a00;
        const f32x4 c1 = half ? a11 : a01;
        const f32x4 c2 = half ? a12 : a02;
        const f32x4 c3 = half ? a13 : a03;

        const int t0 = tbase0 + (half << 4);
        float* ob = out + ((size_t)b * T + t0 + trow) * 256 + (wid << 6) + mrow;
        if (t0 + trow + 3 < T) {
            __builtin_nontemporal_store(c0[0] * rr0, ob + 0*256 +  0);
            __builtin_nontemporal_store(c0[1] * rr1, ob + 1*256 +  0);
            __builtin_nontemporal_store(c0[2] * rr2, ob + 2*256 +  0);
            __builtin_nontemporal_store(c0[3] * rr3, ob + 3*256 +  0);
            __builtin_nontemporal_store(c1[0] * rr0, ob + 0*256 + 16);
            __builtin_nontemporal_store(c1[1] * rr1, ob + 1*256 + 16);
            __builtin_nontemporal_store(c1[2] * rr2, ob + 2*256 + 16);
            __builtin_nontemporal_store(c1[3] * rr3, ob + 3*256 + 16);
            __builtin_nontemporal_store(c2[0] * rr0, ob + 0*256 + 32);
            __builtin_nontemporal_store(c2[1] * rr1, ob + 1*256 + 32);
            __builtin_nontemporal_store(c2[2] * rr2, ob + 2*256 + 32);
            __builtin_nontemporal_store(c2[3] * rr3, ob + 3*256 + 32);
            __builtin_nontemporal_store(c3[0] * rr0, ob + 0*256 + 48);
            __builtin_nontemporal_store(c3[1] * rr1, ob + 1*256 + 48);
            __builtin_nontemporal_store(c3[2] * rr2, ob + 2*256 + 48);
            __builtin_nontemporal_store(c3[3] * rr3, ob + 3*256 + 48);
        }
    }
}

extern "C" void kernel_launch(void* const* d_in, const int* in_sizes, int n_in,
                              void* d_out, int out_size, void* d_ws, size_t ws_size,
                              hipStream_t stream) {
    const int*   durs = (const int*)d_in[1];
    const float* text = (const float*)d_in[0];
    float*       out  = (float*)d_out;

    const int BL = in_sizes[1];        // B * L
    const int D  = in_sizes[0] / BL;   // 256
    const int B  = BL / L;             // 16
    const int T  = out_size / (B * D); // 2048
    const int tilesPerB = (T + BLOCK_TT - 1) / BLOCK_TT;   // 64
    const int nwg = B * tilesPerB;     // 1024

    ge_mfma<<<dim3(nwg), dim3(NTHREADS), 0, stream>>>(durs, text, out, B, T, tilesPerB, nwg);
}

// Round 27
// 14.564 us; speedup vs baseline: 1.0631x; 1.0340x over previous
//
#include <hip/hip_runtime.h>
#include <math.h>

#define L 512
#define LPAD 544          // s_mi padded: rows 512..543 = {0,0} -> p==0 naturally
#define NTHREADS 256
#define BLOCK_TT 32       // two 16-t sub-tiles; shared prologue AND shared B-gather
#define ZWIN 9.0f         // dropped pdf mass <= exp(-40.5): < 1e-10 effect on output
#define NXCD 8

typedef __attribute__((ext_vector_type(8))) short bf16x8;
typedef __attribute__((ext_vector_type(4))) float f32x4;

static constexpr float EPS = 1e-6f;
static constexpr float INV_SQRT_2PI = 0.39894228040143267794f;

union BFrag { unsigned int u[4]; bf16x8 h; };

__global__ __launch_bounds__(NTHREADS, 4) void ge_mfma(
    const int*   __restrict__ durs,  // [B, L]
    const float* __restrict__ text,  // [B, L, 256]
    float*       __restrict__ out,   // [B, T, 256]
    int B, int T, int tilesPerB, int nwg)
{
    __shared__ float2 s_mi[LPAD];

    const int tid  = threadIdx.x;
    const int lane = tid & 63;
    const int wid  = tid >> 6;
    const int g    = lane >> 4;      // k-group (A/B), C row-group
    const int mrow = lane & 15;      // A-row (t offset) == B/C-col (d offset)

    const int orig = blockIdx.x;
    const int wg   = (nwg % NXCD == 0) ? (orig & (NXCD - 1)) * (nwg / NXCD) + (orig >> 3)
                                       : orig;
    const int b      = wg / tilesPerB;
    const int tbase0 = (wg % tilesPerB) * BLOCK_TT;

    // ---- wave-private scan, once per block: lane owns rows 8*lane..8*lane+7 ----
    const int r0 = lane << 3;
    const int4 da = ((const int4*)(durs + (size_t)b * L + r0))[0];
    const int4 db = ((const int4*)(durs + (size_t)b * L + r0))[1];
    int dv[8] = {da.x, da.y, da.z, da.w, db.x, db.y, db.z, db.w};
    int cs[8];
    int run = 0;
    #pragma unroll
    for (int j = 0; j < 8; ++j) { run += dv[j]; cs[j] = run; }
    int v = run;
    #pragma unroll
    for (int off = 1; off < 64; off <<= 1) {
        int n = __shfl_up(v, off, 64);
        if (lane >= off) v += n;
    }
    const int excl = v - run;

    // ---- params to LDS (+ zero pads) + UNION band over the 32-t block ----
    const float tlo = (float)tbase0 + 0.5f;
    const float thi = (float)tbase0 + (float)BLOCK_TT - 0.5f;
    int mn = L, mx = -1;
    #pragma unroll
    for (int j = 0; j < 8; ++j) {
        const float d  = (float)dv[j];
        const float m  = (float)(cs[j] + excl) + 0.5f * d;
        const float sg = 0.5f * d + EPS;
        s_mi[r0 + j] = make_float2(m, 1.0f / sg);
        const float r = ZWIN * sg;
        if (dv[j] >= 1 && m + r >= tlo && m - r <= thi) {
            mn = min(mn, r0 + j);
            mx = max(mx, r0 + j);
        }
    }
    if (lane < LPAD - L) s_mi[L + lane] = make_float2(0.f, 0.f);  // isig==0 -> p==0
    #pragma unroll
    for (int off = 32; off > 0; off >>= 1) {
        mn = min(mn, __shfl_xor(mn, off, 64));
        mx = max(mx, __shfl_xor(mx, off, 64));
    }
    asm volatile("s_waitcnt lgkmcnt(0)" ::: "memory");   // own-wave s_mi writes -> reads
    __builtin_amdgcn_sched_barrier(0);

    // ---- main loop over union band: ONE B-gather feeds BOTH 16-t halves ----
    f32x4 a00 = {0,0,0,0}, a01 = {0,0,0,0}, a02 = {0,0,0,0}, a03 = {0,0,0,0};  // half 0
    f32x4 a10 = {0,0,0,0}, a11 = {0,0,0,0}, a12 = {0,0,0,0}, a13 = {0,0,0,0};  // half 1
    float psum0 = 0.f, psum1 = 0.f;
    const float tf0 = (float)(tbase0 + mrow) + 0.5f;    // half0's t for this lane
    const float tf1 = tf0 + 16.f;                       // half1's t
    const float* tbp = text + (size_t)b * L * 256 + (wid << 6) + mrow;

    for (int kb = (mn & ~7); kb <= mx; kb += 32) {
        const int k0 = kb + (g << 3);

        // B fragments FIRST: issue the 32 independent loads under the A-exp chain
        BFrag B0, B1, B2, B3;
        #pragma unroll
        for (int jp = 0; jp < 4; ++jp) {
            const int ka = min(k0 + 2 * jp,     L - 1);   // p==0 past L-1: garbage*0 == 0
            const int kc = min(k0 + 2 * jp + 1, L - 1);
            const float* ra = tbp + (size_t)ka * 256;
            const float* rc = tbp + (size_t)kc * 256;
            const float b0 = ra[0], b1 = ra[16], b2 = ra[32], b3 = ra[48];
            const float c0 = rc[0], c1 = rc[16], c2 = rc[32], c3 = rc[48];
            asm("v_cvt_pk_bf16_f32 %0, %1, %2" : "=v"(B0.u[jp]) : "v"(b0), "v"(c0));
            asm("v_cvt_pk_bf16_f32 %0, %1, %2" : "=v"(B1.u[jp]) : "v"(b1), "v"(c1));
            asm("v_cvt_pk_bf16_f32 %0, %1, %2" : "=v"(B2.u[jp]) : "v"(b2), "v"(c2));
            asm("v_cvt_pk_bf16_f32 %0, %1, %2" : "=v"(B3.u[jp]) : "v"(b3), "v"(c3));
        }

        // A fragments for both halves (no selects; pads/d==0 underflow to 0 naturally)
        BFrag A0, A1;
        #pragma unroll
        for (int jp = 0; jp < 4; ++jp) {
            const int ka = k0 + 2 * jp;          // <= mx+31 <= 542 < LPAD
            const int kc = ka + 1;
            const float2 mia = s_mi[ka];
            const float2 mic = s_mi[kc];
            const float ca = mia.y * INV_SQRT_2PI;
            const float cc = mic.y * INV_SQRT_2PI;
            const float u0a = (tf0 - mia.x) * mia.y;
            const float u0c = (tf0 - mic.x) * mic.y;
            const float u1a = (tf1 - mia.x) * mia.y;
            const float u1c = (tf1 - mic.x) * mic.y;
            const float p0a = __expf(-0.5f * u0a * u0a) * ca;
            const float p0c = __expf(-0.5f * u0c * u0c) * cc;
            const float p1a = __expf(-0.5f * u1a * u1a) * ca;
            const float p1c = __expf(-0.5f * u1c * u1c) * cc;
            psum0 += p0a + p0c;
            psum1 += p1a + p1c;
            asm("v_cvt_pk_bf16_f32 %0, %1, %2" : "=v"(A0.u[jp]) : "v"(p0a), "v"(p0c));
            asm("v_cvt_pk_bf16_f32 %0, %1, %2" : "=v"(A1.u[jp]) : "v"(p1a), "v"(p1c));
        }

        a00 = __builtin_amdgcn_mfma_f32_16x16x32_bf16(A0.h, B0.h, a00, 0, 0, 0);
        a01 = __builtin_amdgcn_mfma_f32_16x16x32_bf16(A0.h, B1.h, a01, 0, 0, 0);
        a02 = __builtin_amdgcn_mfma_f32_16x16x32_bf16(A0.h, B2.h, a02, 0, 0, 0);
        a03 = __builtin_amdgcn_mfma_f32_16x16x32_bf16(A0.h, B3.h, a03, 0, 0, 0);
        a10 = __builtin_amdgcn_mfma_f32_16x16x32_bf16(A1.h, B0.h, a10, 0, 0, 0);
        a11 = __builtin_amdgcn_mfma_f32_16x16x32_bf16(A1.h, B1.h, a11, 0, 0, 0);
        a12 = __builtin_amdgcn_mfma_f32_16x16x32_bf16(A1.h, B2.h, a12, 0, 0, 0);
        a13 = __builtin_amdgcn_mfma_f32_16x16x32_bf16(A1.h, B3.h, a13, 0, 0, 0);
    }

    // ---- epilogue per half: shuffle-reduced denominators, normalize, nt-store ----
    const int trow = g << 2;
    #pragma unroll
    for (int half = 0; half < 2; ++half) {
        float ps = half ? psum1 : psum0;
        ps += __shfl_xor(ps, 16, 64);
        ps += __shfl_xor(ps, 32, 64);
        const float rn = 1.0f / (ps + EPS);   // lane (g,mrow): denom for t = t0+mrow

        const float rr0 = __shfl(rn, trow + 0, 64);
        const float rr1 = __shfl(rn, trow + 1, 64);
        const float rr2 = __shfl(rn, trow + 2, 64);
        const float rr3 = __shfl(rn, trow + 3, 64);

        const f32x4 c0 = half ? a10 : a00;
        const f32x4 c1 = half ? a11 : a01;
        const f32x4 c2 = half ? a12 : a02;
        const f32x4 c3 = half ? a13 : a03;

        const int t0 = tbase0 + (half << 4);
        float* ob = out + ((size_t)b * T + t0 + trow) * 256 + (wid << 6) + mrow;
        if (t0 + trow + 3 < T) {
            __builtin_nontemporal_store(c0[0] * rr0, ob + 0*256 +  0);
            __builtin_nontemporal_store(c0[1] * rr1, ob + 1*256 +  0);
            __builtin_nontemporal_store(c0[2] * rr2, ob + 2*256 +  0);
            __builtin_nontemporal_store(c0[3] * rr3, ob + 3*256 +  0);
            __builtin_nontemporal_store(c1[0] * rr0, ob + 0*256 + 16);
            __builtin_nontemporal_store(c1[1] * rr1, ob + 1*256 + 16);
            __builtin_nontemporal_store(c1[2] * rr2, ob + 2*256 + 16);
            __builtin_nontemporal_store(c1[3] * rr3, ob + 3*256 + 16);
            __builtin_nontemporal_store(c2[0] * rr0, ob + 0*256 + 32);
            __builtin_nontemporal_store(c2[1] * rr1, ob + 1*256 + 32);
            __builtin_nontemporal_store(c2[2] * rr2, ob + 2*256 + 32);
            __builtin_nontemporal_store(c2[3] * rr3, ob + 3*256 + 32);
            __builtin_nontemporal_store(c3[0] * rr0, ob + 0*256 + 48);
            __builtin_nontemporal_store(c3[1] * rr1, ob + 1*256 + 48);
            __builtin_nontemporal_store(c3[2] * rr2, ob + 2*256 + 48);
            __builtin_nontemporal_store(c3[3] * rr3, ob + 3*256 + 48);
        }
    }
}

extern "C" void kernel_launch(void* const* d_in, const int* in_sizes, int n_in,
                              void* d_out, int out_size, void* d_ws, size_t ws_size,
                              hipStream_t stream) {
    const int*   durs = (const int*)d_in[1];
    const float* text = (const float*)d_in[0];
    float*       out  = (float*)d_out;

    const int BL = in_sizes[1];        // B * L
    const int D  = in_sizes[0] / BL;   // 256
    const int B  = BL / L;             // 16
    const int T  = out_size / (B * D); // 2048
    const int tilesPerB = (T + BLOCK_TT - 1) / BLOCK_TT;   // 64
    const int nwg = B * tilesPerB;     // 1024

    ge_mfma<<<dim3(nwg), dim3(NTHREADS), 0, stream>>>(durs, text, out, B, T, tilesPerB, nwg);
}